// Round 5
// baseline (316.092 us; speedup 1.0000x reference)
//
#include <hip/hip_runtime.h>

#define BATCH 4096
#define ISZ   512
#define MT    8
#define NH    4
#define KS    8
#define NFEAT (NH * ISZ * KS)   // 16384
#define LN_EPS 1e-5f

typedef float vfloat4 __attribute__((ext_vector_type(4)));

// Chebyshev-basis (8 coeffs, poly folded) -> monomial coeffs.
__device__ __forceinline__ void cheb2mono(const float w[8], float4& m0, float4& m1) {
    m0.x = w[0] - w[2] + w[4] - w[6];
    m0.y = w[1] - 3.f*w[3] + 5.f*w[5] - 7.f*w[7];
    m0.z = 2.f*w[2] - 8.f*w[4] + 18.f*w[6];
    m0.w = 4.f*w[3] - 20.f*w[5] + 56.f*w[7];
    m1.x = 8.f*w[4] - 48.f*w[6];
    m1.y = 16.f*w[5] - 112.f*w[7];
    m1.z = 32.f*w[6];
    m1.w = 64.f*w[7];
}

// One thread per feature f: fold poly, convert to monomial, store lane-swizzled
// so w[q] = W2v[(j*8+q)*512 + t] is a contiguous global_load_dwordx4.
__global__ void prep_w2(const float* __restrict__ kern, const float* __restrict__ poly,
                        float4* __restrict__ W2) {
    const int f = blockIdx.x * 256 + threadIdx.x;   // 0..16383
    const int j = f >> 11;                          // f = j*2048 + t*4 + c
    const int t = (f >> 2) & 511;
    const int c = f & 3;
    const int base = (f >> 3) * 64 + (f & 7);       // kernels [h][i][m][k]
    const float p = poly[f];
    float w[8];
    #pragma unroll
    for (int m = 0; m < 8; ++m) w[m] = kern[base + m * 8] * p;
    float4 m0, m1;
    cheb2mono(w, m0, m1);
    W2[(j * 8 + 2 * c    ) * 512 + t] = m0;   // powers 0..3
    W2[(j * 8 + 2 * c + 1) * 512 + t] = m1;   // powers 4..7
}

__device__ __forceinline__ float fast_silu(float d) {
    // exp, add, rcp, mul. rcp(inf)=0 gives correct saturation.
    return d * __builtin_amdgcn_rcpf(1.f + __expf(-d));
}

// Degree-7 Horner: 7 FMA, scalar x input.
__device__ __forceinline__ float horner8(float4 w0, float4 w1, float x) {
    float s = w1.w;
    s = fmaf(s, x, w1.z);
    s = fmaf(s, x, w1.y);
    s = fmaf(s, x, w1.x);
    s = fmaf(s, x, w0.w);
    s = fmaf(s, x, w0.z);
    s = fmaf(s, x, w0.y);
    s = fmaf(s, x, w0.x);
    return s;
}

// Fallback-path weight materialization (no workspace).
__device__ __forceinline__ void make_w(const float* kern, const float* poly,
                                       int f, float4& m0, float4& m1) {
    const int base = (f >> 3) * 64 + (f & 7);
    const float p = poly[f];
    float w[8];
    #pragma unroll
    for (int m = 0; m < 8; ++m) w[m] = kern[base + m * 8] * p;
    cheb2mono(w, m0, m1);
}

// Single-pass: compute each element ONCE, stash in 64 statically-indexed VGPRs,
// then normalize + store from registers. Forced live set ~90 VGPR < 128 cap.
template <bool USE_W2>
__global__ __launch_bounds__(512, 4)   // 128 VGPR cap -> 2 blocks/CU (16 waves)
void cheb_main(const float* __restrict__ x, const float* __restrict__ scale,
               const float4* __restrict__ W2v, const float* __restrict__ kern,
               const float* __restrict__ poly,
               const float* __restrict__ gamma, const float* __restrict__ beta,
               float* __restrict__ out) {
    __shared__ float xs[2][ISZ];   // 4 KB scaled inputs
    __shared__ float red[8][4];    // per-wave LN partials

    const int t  = threadIdx.x;
    const int r0 = blockIdx.x * 2;

    for (int idx = t; idx < 2 * ISZ; idx += 512) {
        const int r = idx >> 9, i = idx & 511;
        xs[r][i] = x[(r0 + r) * ISZ + i] * scale[i];
    }
    __syncthreads();

    // ---- Compute phase: silu(horner) once per element, stash in registers ----
    float st0[32], st1[32];        // static indices only -> stays in VGPRs
    float sum0 = 0.f, sq0 = 0.f, sum1 = 0.f, sq1 = 0.f;

    #pragma unroll
    for (int j = 0; j < 8; ++j) {
        const int i  = ((j & 1) << 8) + (t >> 1);
        const float xa = xs[0][i];   // broadcast LDS reads (lane pairs share addr)
        const float xb = xs[1][i];
        const float4* Wj = W2v + (size_t)j * 8 * 512 + t;
        #pragma unroll
        for (int c = 0; c < 4; ++c) {
            float4 w0, w1;
            if (USE_W2) {
                w0 = Wj[(2 * c) * 512];
                w1 = Wj[(2 * c + 1) * 512];
            } else {
                make_w(kern, poly, j * 2048 + t * 4 + c, w0, w1);
            }
            const float s0 = fast_silu(horner8(w0, w1, xa));
            const float s1 = fast_silu(horner8(w0, w1, xb));
            st0[j * 4 + c] = s0;
            st1[j * 4 + c] = s1;
            sum0 += s0; sq0 = fmaf(s0, s0, sq0);
            sum1 += s1; sq1 = fmaf(s1, s1, sq1);
        }
    }

    // ---- LN reduction: wave butterfly + cross-wave combine ----
    #pragma unroll
    for (int off = 32; off > 0; off >>= 1) {
        sum0 += __shfl_xor(sum0, off, 64);
        sq0  += __shfl_xor(sq0,  off, 64);
        sum1 += __shfl_xor(sum1, off, 64);
        sq1  += __shfl_xor(sq1,  off, 64);
    }
    const int wave = t >> 6;
    if ((t & 63) == 0) {
        red[wave][0] = sum0; red[wave][1] = sq0;
        red[wave][2] = sum1; red[wave][3] = sq1;
    }
    __syncthreads();

    float ts0 = 0.f, tq0 = 0.f, ts1 = 0.f, tq1 = 0.f;
    #pragma unroll
    for (int wv = 0; wv < 8; ++wv) {
        ts0 += red[wv][0]; tq0 += red[wv][1];
        ts1 += red[wv][2]; tq1 += red[wv][3];
    }
    const float invN  = 1.f / (float)NFEAT;
    const float mean0 = ts0 * invN, mean1 = ts1 * invN;
    const float rs0 = rsqrtf(fmaxf(tq0 * invN - mean0 * mean0, 0.f) + LN_EPS);
    const float rs1 = rsqrtf(fmaxf(tq1 * invN - mean1 * mean1, 0.f) + LN_EPS);
    const float nm0 = -mean0 * rs0;
    const float nm1 = -mean1 * rs1;

    // ---- Store phase: normalize stash (2 FMA/elem), nontemporal float4 stores ----
    float* o0 = out + (size_t)r0 * NFEAT;
    float* o1 = o0 + NFEAT;
    #pragma unroll
    for (int j = 0; j < 8; ++j) {
        const int f0 = j * 2048 + t * 4;
        const float4 g  = *(const float4*)(gamma + f0);
        const float4 bb = *(const float4*)(beta  + f0);
        vfloat4 r0v, r1v;
        r0v.x = fmaf(fmaf(st0[j * 4 + 0], rs0, nm0), g.x, bb.x);
        r0v.y = fmaf(fmaf(st0[j * 4 + 1], rs0, nm0), g.y, bb.y);
        r0v.z = fmaf(fmaf(st0[j * 4 + 2], rs0, nm0), g.z, bb.z);
        r0v.w = fmaf(fmaf(st0[j * 4 + 3], rs0, nm0), g.w, bb.w);
        r1v.x = fmaf(fmaf(st1[j * 4 + 0], rs1, nm1), g.x, bb.x);
        r1v.y = fmaf(fmaf(st1[j * 4 + 1], rs1, nm1), g.y, bb.y);
        r1v.z = fmaf(fmaf(st1[j * 4 + 2], rs1, nm1), g.z, bb.z);
        r1v.w = fmaf(fmaf(st1[j * 4 + 3], rs1, nm1), g.w, bb.w);
        __builtin_nontemporal_store(r0v, (vfloat4*)(o0 + f0));
        __builtin_nontemporal_store(r1v, (vfloat4*)(o1 + f0));
    }
}

extern "C" void kernel_launch(void* const* d_in, const int* in_sizes, int n_in,
                              void* d_out, int out_size, void* d_ws, size_t ws_size,
                              hipStream_t stream) {
    const float* x     = (const float*)d_in[0];
    const float* scale = (const float*)d_in[1];
    const float* poly  = (const float*)d_in[2];
    const float* kern  = (const float*)d_in[3];
    const float* gamma = (const float*)d_in[4];
    const float* beta  = (const float*)d_in[5];
    float* out = (float*)d_out;

    const size_t W2_BYTES = (size_t)NFEAT * 8 * sizeof(float);  // 512 KB
    if (ws_size >= W2_BYTES) {
        float4* W2 = (float4*)d_ws;
        prep_w2<<<NFEAT / 256, 256, 0, stream>>>(kern, poly, W2);
        cheb_main<true><<<BATCH / 2, 512, 0, stream>>>(x, scale, (const float4*)W2,
                                                       kern, poly, gamma, beta, out);
    } else {
        cheb_main<false><<<BATCH / 2, 512, 0, stream>>>(x, scale, nullptr,
                                                        kern, poly, gamma, beta, out);
    }
}

// Round 7
// 313.481 us; speedup vs baseline: 1.0083x; 1.0083x over previous
//
#include <hip/hip_runtime.h>

#define BATCH 4096
#define ISZ   512
#define MT    8
#define NH    4
#define KS    8
#define NFEAT (NH * ISZ * KS)   // 16384
#define LN_EPS 1e-5f
#define ROWS  8                  // batch rows per block -> total W2 stream 512 MB

typedef float vfloat4 __attribute__((ext_vector_type(4)));

// Chebyshev-basis (8 coeffs, poly folded) -> monomial coeffs.
__device__ __forceinline__ void cheb2mono(const float w[8], float4& m0, float4& m1) {
    m0.x = w[0] - w[2] + w[4] - w[6];
    m0.y = w[1] - 3.f*w[3] + 5.f*w[5] - 7.f*w[7];
    m0.z = 2.f*w[2] - 8.f*w[4] + 18.f*w[6];
    m0.w = 4.f*w[3] - 20.f*w[5] + 56.f*w[7];
    m1.x = 8.f*w[4] - 48.f*w[6];
    m1.y = 16.f*w[5] - 112.f*w[7];
    m1.z = 32.f*w[6];
    m1.w = 64.f*w[7];
}

// One thread per feature f: fold poly, convert to monomial, store lane-swizzled
// so w[q] = W2v[(j*8+q)*512 + t] is a contiguous global_load_dwordx4.
__global__ void prep_w2(const float* __restrict__ kern, const float* __restrict__ poly,
                        float4* __restrict__ W2) {
    const int f = blockIdx.x * 256 + threadIdx.x;   // 0..16383
    const int j = f >> 11;                          // f = j*2048 + t*4 + c
    const int t = (f >> 2) & 511;
    const int c = f & 3;
    const int base = (f >> 3) * 64 + (f & 7);       // kernels [h][i][m][k]
    const float p = poly[f];
    float w[8];
    #pragma unroll
    for (int m = 0; m < 8; ++m) w[m] = kern[base + m * 8] * p;
    float4 m0, m1;
    cheb2mono(w, m0, m1);
    W2[(j * 8 + 2 * c    ) * 512 + t] = m0;   // powers 0..3
    W2[(j * 8 + 2 * c + 1) * 512 + t] = m1;   // powers 4..7
}

__device__ __forceinline__ float fast_silu(float d) {
    // exp, add, rcp, mul. rcp(inf)=0 gives correct saturation.
    return d * __builtin_amdgcn_rcpf(1.f + __expf(-d));
}

// Degree-7 Horner: 7 FMA, scalar x input.
__device__ __forceinline__ float horner8(float4 w0, float4 w1, float x) {
    float s = w1.w;
    s = fmaf(s, x, w1.z);
    s = fmaf(s, x, w1.y);
    s = fmaf(s, x, w1.x);
    s = fmaf(s, x, w0.w);
    s = fmaf(s, x, w0.z);
    s = fmaf(s, x, w0.y);
    s = fmaf(s, x, w0.x);
    return s;
}

// Fallback-path weight materialization (no workspace).
__device__ __forceinline__ void make_w(const float* kern, const float* poly,
                                       int f, float4& m0, float4& m1) {
    const int base = (f >> 3) * 64 + (f & 7);
    const float p = poly[f];
    float w[8];
    #pragma unroll
    for (int m = 0; m < 8; ++m) w[m] = kern[base + m * 8] * p;
    cheb2mono(w, m0, m1);
}

// Two-pass, ROWS=8: each weight load feeds 8 rows (8x arithmetic intensity vs R0),
// total weight stream 512 MB. Rolled j-loop keeps live-set small (R4-proven).
template <bool USE_W2>
__global__ __launch_bounds__(512, 4)   // 128 VGPR cap -> 2 blocks/CU
void cheb_main(const float* __restrict__ x, const float* __restrict__ scale,
               const float4* __restrict__ W2v, const float* __restrict__ kern,
               const float* __restrict__ poly,
               const float* __restrict__ gamma, const float* __restrict__ beta,
               float* __restrict__ out) {
    __shared__ float xs[ROWS][ISZ];      // 16 KB scaled inputs
    __shared__ float red[8][2 * ROWS];   // per-wave LN partials

    const int t  = threadIdx.x;
    const int r0 = blockIdx.x * ROWS;

    #pragma unroll
    for (int idx = t; idx < ROWS * ISZ; idx += 512) {
        const int r = idx >> 9, i = idx & 511;
        xs[r][i] = x[(r0 + r) * ISZ + i] * scale[i];
    }
    __syncthreads();

    float sum[ROWS], sq[ROWS];
    #pragma unroll
    for (int r = 0; r < ROWS; ++r) { sum[r] = 0.f; sq[r] = 0.f; }

    // ---- Pass A: LN statistics ----
    #pragma unroll 1
    for (int j = 0; j < 8; ++j) {
        const int i = ((j & 1) << 8) + (t >> 1);
        float xv[ROWS];
        #pragma unroll
        for (int r = 0; r < ROWS; ++r) xv[r] = xs[r][i];   // broadcast LDS reads
        const float4* Wj = W2v + (size_t)j * 8 * 512 + t;
        #pragma unroll
        for (int c = 0; c < 4; ++c) {
            float4 w0, w1;
            if (USE_W2) {
                w0 = Wj[(2 * c) * 512];
                w1 = Wj[(2 * c + 1) * 512];
            } else {
                make_w(kern, poly, j * 2048 + t * 4 + c, w0, w1);
            }
            #pragma unroll
            for (int r = 0; r < ROWS; ++r) {
                const float s = fast_silu(horner8(w0, w1, xv[r]));
                sum[r] += s;
                sq[r]   = fmaf(s, s, sq[r]);
            }
        }
    }

    // Wave butterfly + cross-wave combine
    #pragma unroll
    for (int off = 32; off > 0; off >>= 1) {
        #pragma unroll
        for (int r = 0; r < ROWS; ++r) {
            sum[r] += __shfl_xor(sum[r], off, 64);
            sq[r]  += __shfl_xor(sq[r],  off, 64);
        }
    }
    const int wave = t >> 6;
    if ((t & 63) == 0) {
        #pragma unroll
        for (int r = 0; r < ROWS; ++r) {
            red[wave][r]        = sum[r];
            red[wave][ROWS + r] = sq[r];
        }
    }
    __syncthreads();

    float rs[ROWS], nm[ROWS];
    {
        const float invN = 1.f / (float)NFEAT;
        #pragma unroll
        for (int r = 0; r < ROWS; ++r) {
            float ts = 0.f, tq = 0.f;
            #pragma unroll
            for (int wv = 0; wv < 8; ++wv) { ts += red[wv][r]; tq += red[wv][ROWS + r]; }
            const float mean = ts * invN;
            rs[r] = rsqrtf(fmaxf(tq * invN - mean * mean, 0.f) + LN_EPS);
            nm[r] = -mean * rs[r];
        }
    }

    // ---- Pass B: recompute, normalize, nontemporal float4 stores ----
    #pragma unroll 1
    for (int j = 0; j < 8; ++j) {
        const int i  = ((j & 1) << 8) + (t >> 1);
        const int f0 = j * 2048 + t * 4;
        float xv[ROWS];
        #pragma unroll
        for (int r = 0; r < ROWS; ++r) xv[r] = xs[r][i];
        const float4 g  = *(const float4*)(gamma + f0);
        const float4 bb = *(const float4*)(beta  + f0);
        const float4* Wj = W2v + (size_t)j * 8 * 512 + t;
        vfloat4 rv[ROWS];
        #pragma unroll
        for (int c = 0; c < 4; ++c) {
            float4 w0, w1;
            if (USE_W2) {
                w0 = Wj[(2 * c) * 512];
                w1 = Wj[(2 * c + 1) * 512];
            } else {
                make_w(kern, poly, f0 + c, w0, w1);
            }
            const float gc = (c == 0) ? g.x  : (c == 1) ? g.y  : (c == 2) ? g.z  : g.w;
            const float bc = (c == 0) ? bb.x : (c == 1) ? bb.y : (c == 2) ? bb.z : bb.w;
            #pragma unroll
            for (int r = 0; r < ROWS; ++r) {
                const float s = fast_silu(horner8(w0, w1, xv[r]));
                rv[r][c] = fmaf(fmaf(s, rs[r], nm[r]), gc, bc);
            }
        }
        #pragma unroll
        for (int r = 0; r < ROWS; ++r)
            __builtin_nontemporal_store(rv[r],
                (vfloat4*)(out + (size_t)(r0 + r) * NFEAT + f0));
    }
}

extern "C" void kernel_launch(void* const* d_in, const int* in_sizes, int n_in,
                              void* d_out, int out_size, void* d_ws, size_t ws_size,
                              hipStream_t stream) {
    const float* x     = (const float*)d_in[0];
    const float* scale = (const float*)d_in[1];
    const float* poly  = (const float*)d_in[2];
    const float* kern  = (const float*)d_in[3];
    const float* gamma = (const float*)d_in[4];
    const float* beta  = (const float*)d_in[5];
    float* out = (float*)d_out;

    const size_t W2_BYTES = (size_t)NFEAT * 8 * sizeof(float);  // 512 KB
    if (ws_size >= W2_BYTES) {
        float4* W2 = (float4*)d_ws;
        prep_w2<<<NFEAT / 256, 256, 0, stream>>>(kern, poly, W2);
        cheb_main<true><<<BATCH / ROWS, 512, 0, stream>>>(x, scale, (const float4*)W2,
                                                          kern, poly, gamma, beta, out);
    } else {
        cheb_main<false><<<BATCH / ROWS, 512, 0, stream>>>(x, scale, nullptr,
                                                           kern, poly, gamma, beta, out);
    }
}